// Round 6
// baseline (179.369 us; speedup 1.0000x reference)
//
#include <hip/hip_runtime.h>
#include <hip/hip_bf16.h>
#include <hip/hip_fp16.h>
#include <stdint.h>

typedef __attribute__((ext_vector_type(8))) _Float16 f16x8;
typedef __attribute__((ext_vector_type(4))) float f32x4;

#define B_  32
#define S_  512
#define K_  512
#define H_  1024
#define HS  64           // h-cols per block
#define SC  128          // s-rows per chunk
#define NKT 8            // K_/64
#define NSC 4            // S_/SC

// LDS: W0 @0 [192 rows][64 K] f16 (24576B) | W1 @24576 (24576B) | extra @49152 (10240B)
// zf ALIASES W1+extra: @24576, 128 s-rows x 272B (64 (z,f) f16 pairs + 16B pad).
// Parity: kt reads W[kt&1], stages W[(kt&1)^1]; kt7 pre-stages next chunk's kt0
// into W0 (W data is sc-invariant), leaving W1 dead for zf during epi/scan/out.
// Banking: zf row stride 272B -> fq-group (4-row) stride = 16 banks; fr stride
// 1 bank -> every access pattern is <=2 lanes/bank (free).
#define W0_OFF 0
#define W1_OFF 24576
#define ZF_OFF 24576
#define ZROWB  272
#define LDS_BYTES 59392   /* 2 blocks/CU (118784 <= 163840) */

#define GLDS(src, dst) __builtin_amdgcn_global_load_lds( \
    (const __attribute__((address_space(1))) void*)(src), \
    (__attribute__((address_space(3))) void*)(dst), 16, 0, 0)

__device__ inline float sigm(float v) {
    return __builtin_amdgcn_rcpf(1.f + __expf(-v));
}

// ---------------------------------------------------------------------------
// f32 -> f16 conversion for x and W. 8 elems/thread, 16B stores.
// ---------------------------------------------------------------------------
struct alignas(16) H8 { _Float16 h[8]; };

__global__ __launch_bounds__(256) void cvt_xw(
    const float* __restrict__ x, _Float16* __restrict__ xh, int n8x,
    const float* __restrict__ W, _Float16* __restrict__ Wh, int n8w)
{
    const int t = blockIdx.x * 256 + threadIdx.x;
    const float* src; _Float16* dst; int i;
    if (t < n8x)             { src = x; dst = xh; i = t; }
    else if (t < n8x + n8w)  { src = W; dst = Wh; i = t - n8x; }
    else return;
    const float4* p = (const float4*)(src + (size_t)i * 8);
    const float4 a = p[0], b = p[1];
    H8 o;
    o.h[0] = (_Float16)a.x; o.h[1] = (_Float16)a.y;
    o.h[2] = (_Float16)a.z; o.h[3] = (_Float16)a.w;
    o.h[4] = (_Float16)b.x; o.h[5] = (_Float16)b.y;
    o.h[6] = (_Float16)b.z; o.h[7] = (_Float16)b.w;
    ((H8*)dst)[i] = o;
}

// ---------------------------------------------------------------------------
// Fused GEMM + activations + scan + output.
// Grid 512 = (b, hs), XCD-affine (each XCD sees 4 b's -> x slice L2-resident).
// Block 256 = 4 waves (2 sw x 2 gw); wave tile 64 s x 96 g, acc 4x6.
// A-frags: DIRECT global->VGPR dwordx4 (8 contiguous f16 per frag), double-
// buffered in regs, prefetched one kt ahead. W: LDS double-buffer via
// global_load_lds w16 + XOR swizzle; ONE barrier per kt.
// ---------------------------------------------------------------------------
__global__ __launch_bounds__(256, 2) void qrnn_fused(
    const _Float16* __restrict__ xh,   // [B*S, K]
    const _Float16* __restrict__ Wh,   // [3H, K]
    const float* __restrict__ bias,    // [3H]
    const float* __restrict__ c0,      // [B, H]
    float* __restrict__ out)           // [B,S,H] ++ [B,H]
{
    extern __shared__ char smem[];

    const int tid  = threadIdx.x;
    const int lane = tid & 63;
    const int wid  = tid >> 6;
    const int gw   = wid & 1;          // gate-col strip (96 of 192)
    const int sw   = wid >> 1;         // s-half (64 of 128)
    const int fq   = lane >> 4;
    const int fr   = lane & 15;

    const int bid = blockIdx.x;
    const int b   = (bid & 7) + ((bid >> 7) << 3);
    const int hs  = (bid >> 3) & 15;

    float bias_r[6];
    #pragma unroll
    for (int n = 0; n < 6; ++n) {
        const int g = gw * 96 + n * 16 + fr;
        bias_r[n] = bias[(g >> 6) * H_ + hs * HS + (g & 63)];
    }

    float c = 0.f;
    if (tid < HS) c = c0[b * H_ + hs * HS + tid];

    const int srow  = lane >> 3;
    const int scolb = (((lane & 7) ^ (lane >> 3)) << 4);
    const _Float16* xbase = xh + (size_t)(b * S_) * K_;

    // A-frag register double buffer: af[buf][ks][m]
    f16x8 af[2][2][4];

    auto LOADA = [&](int sc_, int kt_, f16x8 (&dst)[2][4]) {
        #pragma unroll
        for (int ks = 0; ks < 2; ++ks)
            #pragma unroll
            for (int m = 0; m < 4; ++m) {
                const _Float16* p = xbase
                    + (size_t)(sc_ * SC + sw * 64 + m * 16 + fr) * K_
                    + kt_ * 64 + ks * 32 + fq * 8;
                dst[ks][m] = *(const f16x8*)p;
            }
    };

    auto STAGEW = [&](int kt_, int bufoff) {
        #pragma unroll
        for (int i = 0; i < 6; ++i) {
            const int cid = wid * 6 + i;          // 0..23 chunks of 1KB
            const int r   = cid * 8 + srow;       // 0..191
            const int wrow = (r >> 6) * H_ + hs * HS + (r & 63);
            const char* src = (const char*)(Wh + (size_t)wrow * K_ + kt_ * 64) + scolb;
            GLDS(src, smem + bufoff + cid * 1024);
        }
    };

    LOADA(0, 0, af[0]);
    STAGEW(0, W0_OFF);
    __syncthreads();

    char* zfb = smem + ZF_OFF;

    for (int sc = 0; sc < NSC; ++sc) {
        f32x4 acc[4][6] = {};

        #pragma unroll
        for (int kt = 0; kt < NKT; ++kt) {
            const int cur    = kt & 1;
            const int curoff = cur ? W1_OFF : W0_OFF;
            const int nxtoff = cur ? W0_OFF : W1_OFF;
            if (kt < NKT - 1) {
                LOADA(sc, kt + 1, af[cur ^ 1]);
                STAGEW(kt + 1, nxtoff);
            } else if (sc + 1 < NSC) {
                LOADA(sc + 1, 0, af[cur ^ 1]);
                STAGEW(0, nxtoff);      // same W data (sc-invariant)
            }
            #pragma unroll
            for (int ks = 0; ks < 2; ++ks) {
                f16x8 bf[6];
                #pragma unroll
                for (int n = 0; n < 6; ++n) {
                    const int row = gw * 96 + n * 16 + fr;
                    const int kb  = ks * 64 + fq * 16;
                    bf[n] = *(const f16x8*)(smem + curoff + row * 128 + (kb ^ ((row & 7) << 4)));
                }
                __builtin_amdgcn_s_setprio(1);
                #pragma unroll
                for (int m = 0; m < 4; ++m)
                    #pragma unroll
                    for (int n = 0; n < 6; ++n)
                        acc[m][n] = __builtin_amdgcn_mfma_f32_16x16x32_f16(
                            af[cur][ks][m], bf[n], acc[m][n], 0, 0, 0);
                __builtin_amdgcn_s_setprio(0);
            }
            __syncthreads();   // stage landed; bf reads done before re-stage
        }

        // ---- epilogue: z (tanh) / f (sigm) -> zf pairs (aliases dead W1) ----
        #pragma unroll
        for (int n = 0; n < 6; ++n) {
            const int gbase = gw * 96 + n * 16;
            const int gate  = gbase >> 6;
            if (gate == 2) continue;               // o stays in acc
            const int h = (gbase & 63) + fr;
            #pragma unroll
            for (int m = 0; m < 4; ++m) {
                #pragma unroll
                for (int j = 0; j < 4; ++j) {
                    const int sl  = sw * 64 + m * 16 + fq * 4 + j;
                    const float v = acc[m][n][j] + bias_r[n];
                    const float a = (gate == 0)
                        ? 2.f * sigm(2.f * v) - 1.f   // tanh
                        : sigm(v);
                    *(_Float16*)(zfb + sl * ZROWB + h * 4 + gate * 2) = (_Float16)a;
                }
            }
        }
        __syncthreads();

        // ---- scan: wave0, one h-col per lane; (z,f) in one b32; c -> z slot -
        if (tid < HS) {
            #pragma unroll 8
            for (int s = 0; s < SC; ++s) {
                const uint32_t pr = *(const uint32_t*)(zfb + s * ZROWB + tid * 4);
                union { uint16_t u; _Float16 hv; } lo, hi;
                lo.u = (uint16_t)(pr & 0xffffu);
                hi.u = (uint16_t)(pr >> 16);
                const float z = (float)lo.hv;
                const float f = (float)hi.hv;
                c = __builtin_fmaf(f, c - z, z);     // f*c + (1-f)*z
                *(_Float16*)(zfb + s * ZROWB + tid * 4) = (_Float16)c;
            }
        }
        __syncthreads();

        // ---- out: gw1 waves own all o-cols (n=2..5): sigm(acc)*c -> f32 out -
        if (gw == 1) {
            #pragma unroll
            for (int n = 2; n < 6; ++n) {
                const int h = (n - 2) * 16 + fr;
                #pragma unroll
                for (int m = 0; m < 4; ++m) {
                    #pragma unroll
                    for (int j = 0; j < 4; ++j) {
                        const int sl  = sw * 64 + m * 16 + fq * 4 + j;
                        const float o = sigm(acc[m][n][j] + bias_r[n]);
                        const float cc = (float)*(const _Float16*)(zfb + sl * ZROWB + h * 4);
                        out[(size_t)(b * S_ + sc * SC + sl) * H_ + hs * HS + h] = o * cc;
                    }
                }
            }
        }
        __syncthreads();   // zf consumed before next chunk's kt0 stages W1
    }

    // c_last tail: [1,B,H] appended after [B,S,H]
    if (tid < HS) out[(size_t)B_ * S_ * H_ + b * H_ + hs * HS + tid] = c;
}

extern "C" void kernel_launch(void* const* d_in, const int* in_sizes, int n_in,
                              void* d_out, int out_size, void* d_ws, size_t ws_size,
                              hipStream_t stream) {
    const float* x = (const float*)d_in[0];
    const float* h = (const float*)d_in[1];
    const float* W = (const float*)d_in[2];
    const float* b = (const float*)d_in[3];
    float* out = (float*)d_out;

    _Float16* xh = (_Float16*)d_ws;
    _Float16* Wh = xh + (size_t)B_ * S_ * K_;

    hipFuncSetAttribute((const void*)qrnn_fused,
                        hipFuncAttributeMaxDynamicSharedMemorySize, LDS_BYTES);

    const int n8x = B_ * S_ * K_ / 8;   // 1048576
    const int n8w = 3 * H_ * K_ / 8;    // 196608
    cvt_xw<<<(n8x + n8w + 255) / 256, 256, 0, stream>>>(x, xh, n8x, W, Wh, n8w);

    qrnn_fused<<<B_ * (H_ / HS), 256, LDS_BYTES, stream>>>(xh, Wh, b, h, out);
}

// Round 7
// 154.563 us; speedup vs baseline: 1.1605x; 1.1605x over previous
//
#include <hip/hip_runtime.h>
#include <hip/hip_bf16.h>
#include <hip/hip_fp16.h>
#include <stdint.h>

typedef __attribute__((ext_vector_type(8))) _Float16 f16x8;
typedef __attribute__((ext_vector_type(4))) float f32x4;

#define B_  32
#define S_  512
#define K_  512
#define H_  1024
#define HS  64           // h-cols per block
#define SC  128          // s-rows per chunk
#define NKT 8            // K_/64
#define NSC 4            // S_/SC

// LDS: W0 @0 (24576B) | W1 @24576 (24576B). Total 48KB.
// zf ALIASES [0..33792): 128 s-rows x 264B, each row = 64 packed (z,f) f16
// pairs (u32). Valid only between the post-K-loop barrier and the out-phase
// barrier (both W buffers dead there); each chunk restages W kt0 afterwards.
// Banking: row stride 264B = 66 words (2 mod 32); fq-group stride 4 rows =
// 264 words (8 mod 32); fr stride 1 word -> every burst is <=2 lanes/bank.
#define W0_OFF 0
#define W1_OFF 24576
#define ZROWB  264
#define LDS_BYTES 49152   /* 48KB */

#define GLDS(src, dst) __builtin_amdgcn_global_load_lds( \
    (const __attribute__((address_space(1))) void*)(src), \
    (__attribute__((address_space(3))) void*)(dst), 16, 0, 0)

__device__ inline float sigm(float v) {
    return __builtin_amdgcn_rcpf(1.f + __expf(-v));
}

// ---------------------------------------------------------------------------
// f32 -> f16 conversion for x and W. 8 elems/thread, 16B stores.
// ---------------------------------------------------------------------------
struct alignas(16) H8 { _Float16 h[8]; };

__global__ __launch_bounds__(256) void cvt_xw(
    const float* __restrict__ x, _Float16* __restrict__ xh, int n8x,
    const float* __restrict__ W, _Float16* __restrict__ Wh, int n8w)
{
    const int t = blockIdx.x * 256 + threadIdx.x;
    const float* src; _Float16* dst; int i;
    if (t < n8x)             { src = x; dst = xh; i = t; }
    else if (t < n8x + n8w)  { src = W; dst = Wh; i = t - n8x; }
    else return;
    const float4* p = (const float4*)(src + (size_t)i * 8);
    const float4 a = p[0], b = p[1];
    H8 o;
    o.h[0] = (_Float16)a.x; o.h[1] = (_Float16)a.y;
    o.h[2] = (_Float16)a.z; o.h[3] = (_Float16)a.w;
    o.h[4] = (_Float16)b.x; o.h[5] = (_Float16)b.y;
    o.h[6] = (_Float16)b.z; o.h[7] = (_Float16)b.w;
    ((H8*)dst)[i] = o;
}

// ---------------------------------------------------------------------------
// Fused GEMM + activations + scan + output.
// Grid 512 = (b, hs), XCD-affine (each XCD sees 4 b's -> x slice L2-resident).
// Block 256 = 4 waves (2 sw x 2 gw); wave tile 64 s x 96 g, acc 4x6.
// A-frags: direct global->VGPR (single kt buffer, 32 VGPR; x is L2-hot).
// W: LDS double-buffer via global_load_lds w16 + XOR swizzle, ONE barrier/kt.
// Per kt: [barrier] load af(kt) -> STAGE W(kt+1)->nxt -> {bf ds_reads(cur),
// MFMA} x2ks. Epilogue z/f -> packed zf LDS (aliases W). Scan by wave0.
// Out: gw1 waves sigm(o-acc)*c -> f32 out.
// ---------------------------------------------------------------------------
__global__ __launch_bounds__(256, 2) void qrnn_fused(
    const _Float16* __restrict__ xh,   // [B*S, K]
    const _Float16* __restrict__ Wh,   // [3H, K]
    const float* __restrict__ bias,    // [3H]
    const float* __restrict__ c0,      // [B, H]
    float* __restrict__ out)           // [B,S,H] ++ [B,H]
{
    extern __shared__ char smem[];

    const int tid  = threadIdx.x;
    const int lane = tid & 63;
    const int wid  = tid >> 6;
    const int gw   = wid & 1;          // gate-col strip (96 of 192)
    const int sw   = wid >> 1;         // s-half (64 of 128)
    const int fq   = lane >> 4;
    const int fr   = lane & 15;

    const int bid = blockIdx.x;
    const int b   = (bid & 7) + ((bid >> 7) << 3);
    const int hs  = (bid >> 3) & 15;

    float bias_r[6];
    #pragma unroll
    for (int n = 0; n < 6; ++n) {
        const int g = gw * 96 + n * 16 + fr;
        bias_r[n] = bias[(g >> 6) * H_ + hs * HS + (g & 63)];
    }

    float c = 0.f;
    if (tid < HS) c = c0[b * H_ + hs * HS + tid];

    const int srow  = lane >> 3;
    const int scolb = (((lane & 7) ^ (lane >> 3)) << 4);
    const _Float16* xbase = xh + (size_t)(b * S_) * K_;
    // per-lane A row pointer (row = sc*128 + sw*64 + m*16 + fr)
    const _Float16* arow = xbase + (size_t)(sw * 64 + fr) * K_;

    auto STAGEW = [&](int kt_, int bufoff) {
        #pragma unroll
        for (int i = 0; i < 6; ++i) {
            const int cid = wid * 6 + i;          // 0..23 chunks of 1KB
            const int r   = cid * 8 + srow;       // 0..191
            const int wrow = (r >> 6) * H_ + hs * HS + (r & 63);
            const char* src = (const char*)(Wh + (size_t)wrow * K_ + kt_ * 64) + scolb;
            GLDS(src, smem + bufoff + cid * 1024);
        }
    };

    char* zfb = smem;   // aliases W0+W1 during epi/scan/out

    for (int sc = 0; sc < NSC; ++sc) {
        // restage W kt0 into W0 (zf region dead again after out-barrier)
        STAGEW(0, W0_OFF);
        __syncthreads();

        f32x4 acc[4][6] = {};
        const _Float16* achunk = arow + (size_t)(sc * SC) * K_;

        #pragma unroll
        for (int kt = 0; kt < NKT; ++kt) {
            const int cur    = kt & 1;
            const int curoff = cur ? W1_OFF : W0_OFF;
            const int nxtoff = cur ? W0_OFF : W1_OFF;

            // A-frags for this kt: 8 x dwordx4, L2-hot
            f16x8 af[2][4];
            #pragma unroll
            for (int ks = 0; ks < 2; ++ks)
                #pragma unroll
                for (int m = 0; m < 4; ++m)
                    af[ks][m] = *(const f16x8*)(achunk + (size_t)(m * 16) * K_
                                                + kt * 64 + ks * 32 + fq * 8);

            if (kt + 1 < NKT) STAGEW(kt + 1, nxtoff);   // hides under MFMA

            #pragma unroll
            for (int ks = 0; ks < 2; ++ks) {
                f16x8 bf[6];
                #pragma unroll
                for (int n = 0; n < 6; ++n) {
                    const int row = gw * 96 + n * 16 + fr;
                    const int kb  = ks * 64 + fq * 16;
                    bf[n] = *(const f16x8*)(smem + curoff + row * 128 + (kb ^ ((row & 7) << 4)));
                }
                __builtin_amdgcn_s_setprio(1);
                #pragma unroll
                for (int m = 0; m < 4; ++m)
                    #pragma unroll
                    for (int n = 0; n < 6; ++n)
                        acc[m][n] = __builtin_amdgcn_mfma_f32_16x16x32_f16(
                            af[ks][m], bf[n], acc[m][n], 0, 0, 0);
                __builtin_amdgcn_s_setprio(0);
            }
            __syncthreads();   // stage(kt+1) landed; cur reads done before re-stage
        }

        // ---- epilogue: z (tanh) / f (sigm) -> packed zf pairs (aliases W) ---
        #pragma unroll
        for (int n = 0; n < 6; ++n) {
            const int gbase = gw * 96 + n * 16;
            const int gate  = gbase >> 6;
            if (gate == 2) continue;               // o stays in acc
            const int h = (gbase & 63) + fr;
            #pragma unroll
            for (int m = 0; m < 4; ++m) {
                #pragma unroll
                for (int j = 0; j < 4; ++j) {
                    const int sl  = sw * 64 + m * 16 + fq * 4 + j;
                    const float v = acc[m][n][j] + bias_r[n];
                    const float a = (gate == 0)
                        ? 2.f * sigm(2.f * v) - 1.f   // tanh
                        : sigm(v);
                    *(_Float16*)(zfb + sl * ZROWB + h * 4 + gate * 2) = (_Float16)a;
                }
            }
        }
        __syncthreads();

        // ---- scan: wave0, one h-col per lane; (z,f) one b32; c -> z slot ----
        if (tid < HS) {
            #pragma unroll 8
            for (int s = 0; s < SC; ++s) {
                const uint32_t pr = *(const uint32_t*)(zfb + s * ZROWB + tid * 4);
                union { uint16_t u; _Float16 hv; } lo, hi;
                lo.u = (uint16_t)(pr & 0xffffu);
                hi.u = (uint16_t)(pr >> 16);
                const float z = (float)lo.hv;
                const float f = (float)hi.hv;
                c = __builtin_fmaf(f, c - z, z);     // f*c + (1-f)*z
                *(_Float16*)(zfb + s * ZROWB + tid * 4) = (_Float16)c;
            }
        }
        __syncthreads();

        // ---- out: gw1 waves own all o-cols (n=2..5): sigm(acc)*c -> f32 -----
        if (gw == 1) {
            #pragma unroll
            for (int n = 2; n < 6; ++n) {
                const int h = (n - 2) * 16 + fr;
                #pragma unroll
                for (int m = 0; m < 4; ++m) {
                    #pragma unroll
                    for (int j = 0; j < 4; ++j) {
                        const int sl  = sw * 64 + m * 16 + fq * 4 + j;
                        const float o = sigm(acc[m][n][j] + bias_r[n]);
                        const float cc = (float)*(const _Float16*)(zfb + sl * ZROWB + h * 4);
                        out[(size_t)(b * S_ + sc * SC + sl) * H_ + hs * HS + h] = o * cc;
                    }
                }
            }
        }
        __syncthreads();   // zf fully consumed before next chunk's W restage
    }

    // c_last tail: [1,B,H] appended after [B,S,H]
    if (tid < HS) out[(size_t)B_ * S_ * H_ + b * H_ + hs * HS + tid] = c;
}

extern "C" void kernel_launch(void* const* d_in, const int* in_sizes, int n_in,
                              void* d_out, int out_size, void* d_ws, size_t ws_size,
                              hipStream_t stream) {
    const float* x = (const float*)d_in[0];
    const float* h = (const float*)d_in[1];
    const float* W = (const float*)d_in[2];
    const float* b = (const float*)d_in[3];
    float* out = (float*)d_out;

    _Float16* xh = (_Float16*)d_ws;
    _Float16* Wh = xh + (size_t)B_ * S_ * K_;

    hipFuncSetAttribute((const void*)qrnn_fused,
                        hipFuncAttributeMaxDynamicSharedMemorySize, LDS_BYTES);

    const int n8x = B_ * S_ * K_ / 8;   // 1048576
    const int n8w = 3 * H_ * K_ / 8;    // 196608
    cvt_xw<<<(n8x + n8w + 255) / 256, 256, 0, stream>>>(x, xh, n8x, W, Wh, n8w);

    qrnn_fused<<<B_ * (H_ / HS), 256, LDS_BYTES, stream>>>(xh, Wh, b, h, out);
}

// Round 8
// 82.907 us; speedup vs baseline: 2.1635x; 1.8643x over previous
//
#include <hip/hip_runtime.h>
#include <hip/hip_bf16.h>
#include <hip/hip_fp16.h>
#include <stdint.h>

typedef __attribute__((ext_vector_type(8))) _Float16 f16x8;
typedef __attribute__((ext_vector_type(4))) float f32x4;

#define B_  32
#define S_  512
#define K_  512
#define H_  1024
#define HS  64           // h-cols per block
#define SC  128          // s-rows per chunk
#define NKT 8            // K_/64
#define NSC 4            // S_/SC

// LDS: x dbuf 2x16K | W dbuf 2x24K = 80KB -> 2 blocks/CU.
// handoff (2 sw x 64 h x {F,G} f32 = 1KB) aliases the WD1 tail: WD1 is dead
// after kt7's barrier (kt7 reads buf1, last stage went to buf0), and is next
// written by kt0's stage (into buf1) only after the chunk-end barrier.
#define XD0 0
#define XD1 16384
#define WD0 32768
#define WD1 57344
#define HOF (WD1 + 24576 - 1024)
#define LDS_BYTES 81920

#define GLDS(src, dst) __builtin_amdgcn_global_load_lds( \
    (const __attribute__((address_space(1))) void*)(src), \
    (__attribute__((address_space(3))) void*)(dst), 16, 0, 0)

__device__ inline float sigm(float v) {
    return __builtin_amdgcn_rcpf(1.f + __expf(-v));
}

// ---------------------------------------------------------------------------
// f32 -> f16 conversion for x and W. 8 elems/thread, 16B stores.
// ---------------------------------------------------------------------------
struct alignas(16) H8 { _Float16 h[8]; };

__global__ __launch_bounds__(256) void cvt_xw(
    const float* __restrict__ x, _Float16* __restrict__ xh, int n8x,
    const float* __restrict__ W, _Float16* __restrict__ Wh, int n8w)
{
    const int t = blockIdx.x * 256 + threadIdx.x;
    const float* src; _Float16* dst; int i;
    if (t < n8x)             { src = x; dst = xh; i = t; }
    else if (t < n8x + n8w)  { src = W; dst = Wh; i = t - n8x; }
    else return;
    const float4* p = (const float4*)(src + (size_t)i * 8);
    const float4 a = p[0], b = p[1];
    H8 o;
    o.h[0] = (_Float16)a.x; o.h[1] = (_Float16)a.y;
    o.h[2] = (_Float16)a.z; o.h[3] = (_Float16)a.w;
    o.h[4] = (_Float16)b.x; o.h[5] = (_Float16)b.y;
    o.h[6] = (_Float16)b.z; o.h[7] = (_Float16)b.w;
    ((H8*)dst)[i] = o;
}

// ---------------------------------------------------------------------------
// Fused GEMM + activations + IN-REGISTER affine scan + output.
// Grid 512 = (b, hs) XCD-affine. Block 256 = 4 waves (sw x gw); wave tile
// 64 s x {z,f,o} x 32 h (n = gate*2+nn, frag row = gate*64 + gw*32 + nn*16).
// K-loop: 1 barrier/kt (stage nxt buf -> ds_read cur frags -> MFMA -> sync).
// Scan: c <- f*c + (1-f)z is affine; per-lane run composition + fq
// Kogge-Stone (shfl) + per-h (F,G) handoff between sw waves via 1KB LDS.
// Backfill replays steps in-register and writes f32 out directly.
// ---------------------------------------------------------------------------
__global__ __launch_bounds__(256, 2) void qrnn_fused(
    const _Float16* __restrict__ xh,   // [B*S, K]
    const _Float16* __restrict__ Wh,   // [3H, K]
    const float* __restrict__ bias,    // [3H]
    const float* __restrict__ c0,      // [B, H]
    float* __restrict__ out)           // [B,S,H] ++ [B,H]
{
    extern __shared__ char smem[];

    const int tid  = threadIdx.x;
    const int lane = tid & 63;
    const int wid  = tid >> 6;
    const int gw   = wid & 1;          // h-half (32 h)
    const int sw   = wid >> 1;         // s-half (64 s)
    const int fq   = lane >> 4;
    const int fr   = lane & 15;

    const int bid = blockIdx.x;
    const int b   = (bid & 7) + ((bid >> 7) << 3);
    const int hs  = (bid >> 3) & 15;

    // per-lane h columns (nn = 0,1) and bias
    float bz[2], bff[2], bo[2], cc[2];
    #pragma unroll
    for (int nn = 0; nn < 2; ++nn) {
        const int hcol = hs * HS + gw * 32 + nn * 16 + fr;
        bz[nn]  = bias[hcol];
        bff[nn] = bias[H_ + hcol];
        bo[nn]  = bias[2 * H_ + hcol];
        cc[nn]  = c0[b * H_ + hcol];
    }

    const int srow  = lane >> 3;
    const int scolb = (((lane & 7) ^ (lane >> 3)) << 4);
    const _Float16* xbase = xh + (size_t)(b * S_) * K_;

    auto STAGE = [&](int sc_, int kt_, int xoff, int woff) {
        #pragma unroll
        for (int i = 0; i < 10; ++i) {
            const int cid = wid * 10 + i;          // 0..39 chunks of 1KB
            if (cid < 16) {                        // x tile rows (s')
                const int r = cid * 8 + srow;
                const char* src = (const char*)(xbase + (size_t)(sc_ * SC + r) * K_ + kt_ * 64) + scolb;
                GLDS(src, smem + xoff + cid * 1024);
            } else {                               // W tile rows (0..191)
                const int r = (cid - 16) * 8 + srow;
                const int wrow = (r >> 6) * H_ + hs * HS + (r & 63);
                const char* src = (const char*)(Wh + (size_t)wrow * K_ + kt_ * 64) + scolb;
                GLDS(src, smem + woff + (cid - 16) * 1024);
            }
        }
    };

    STAGE(0, 0, XD0, WD0);
    __syncthreads();

    for (int sc = 0; sc < NSC; ++sc) {
        f32x4 acc[4][6] = {};

        #pragma unroll
        for (int kt = 0; kt < NKT; ++kt) {
            const int cur  = kt & 1;
            const int curx = cur ? XD1 : XD0;
            const int curw = cur ? WD1 : WD0;
            const int nxtx = cur ? XD0 : XD1;
            const int nxtw = cur ? WD0 : WD1;

            if (kt + 1 < NKT)      STAGE(sc, kt + 1, nxtx, nxtw);
            else if (sc + 1 < NSC) STAGE(sc + 1, 0, nxtx, nxtw);  // kt7 -> buf0

            f16x8 af[2][4], bf[2][6];
            #pragma unroll
            for (int ks = 0; ks < 2; ++ks) {
                #pragma unroll
                for (int m = 0; m < 4; ++m) {
                    const int row = sw * 64 + m * 16 + fr;
                    const int kb  = ks * 64 + fq * 16;
                    af[ks][m] = *(const f16x8*)(smem + curx + row * 128 + (kb ^ ((row & 7) << 4)));
                }
                #pragma unroll
                for (int n = 0; n < 6; ++n) {
                    const int row = (n >> 1) * 64 + gw * 32 + (n & 1) * 16 + fr;
                    const int kb  = ks * 64 + fq * 16;
                    bf[ks][n] = *(const f16x8*)(smem + curw + row * 128 + (kb ^ ((row & 7) << 4)));
                }
            }
            __builtin_amdgcn_s_setprio(1);
            #pragma unroll
            for (int ks = 0; ks < 2; ++ks)
                #pragma unroll
                for (int m = 0; m < 4; ++m)
                    #pragma unroll
                    for (int n = 0; n < 6; ++n)
                        acc[m][n] = __builtin_amdgcn_mfma_f32_16x16x32_f16(
                            af[ks][m], bf[ks][n], acc[m][n], 0, 0, 0);
            __builtin_amdgcn_s_setprio(0);
            __syncthreads();   // stage landed; cur reads done before reuse
        }

        // ---- activations + per-lane affine composition ----------------------
        // step: c <- f*c + g, g = (1-f)*z. acc slots after this pass:
        // [m][nn] = g, [m][2+nn] = f, [m][4+nn] = o (all f32).
        float FsS[2][4], GsS[2][4];   // chunk-start -> run(m)-start coeffs
        float FP[2], GP[2];           // wave-total map (exclusive prefix over m)
        #pragma unroll
        for (int nn = 0; nn < 2; ++nn) {
            FP[nn] = 1.f; GP[nn] = 0.f;
            #pragma unroll
            for (int m = 0; m < 4; ++m) {
                float Fr = 1.f, Gr = 0.f;
                #pragma unroll
                for (int j = 0; j < 4; ++j) {
                    const float z = 2.f * sigm(2.f * (acc[m][nn][j] + bz[nn])) - 1.f;
                    const float f = sigm(acc[m][2 + nn][j] + bff[nn]);
                    const float g = (1.f - f) * z;
                    acc[m][nn][j]     = g;
                    acc[m][2 + nn][j] = f;
                    acc[m][4 + nn][j] = sigm(acc[m][4 + nn][j] + bo[nn]);
                    Gr = __builtin_fmaf(f, Gr, g);
                    Fr = f * Fr;
                }
                // Kogge-Stone over fq (4 groups of 16 lanes)
                float F1 = __shfl(Fr, lane - 16), G1 = __shfl(Gr, lane - 16);
                if (fq >= 1) { Gr = __builtin_fmaf(Fr, G1, Gr); Fr = Fr * F1; }
                float F2 = __shfl(Fr, lane - 32), G2 = __shfl(Gr, lane - 32);
                if (fq >= 2) { Gr = __builtin_fmaf(Fr, G2, Gr); Fr = Fr * F2; }
                float FE = __shfl(Fr, lane - 16), GE = __shfl(Gr, lane - 16);
                if (fq == 0) { FE = 1.f; GE = 0.f; }
                const float FM = __shfl(Fr, 48 + fr);   // full 16-step map of m
                const float GM = __shfl(Gr, 48 + fr);
                FsS[nn][m] = FE * FP[nn];
                GsS[nn][m] = __builtin_fmaf(FE, GP[nn], GE);
                GP[nn] = __builtin_fmaf(FM, GP[nn], GM);
                FP[nn] = FM * FP[nn];
            }
        }

        // ---- handoff: per-h wave-total (F,G) between sw waves ---------------
        if (fq == 0) {
            #pragma unroll
            for (int nn = 0; nn < 2; ++nn) {
                const int hh = gw * 32 + nn * 16 + fr;
                *(float2*)(smem + HOF + sw * 512 + hh * 8) = make_float2(FP[nn], GP[nn]);
            }
        }
        asm volatile("s_waitcnt lgkmcnt(0)" ::: "memory");
        __builtin_amdgcn_s_barrier();

        // ---- backfill + out stores ------------------------------------------
        #pragma unroll
        for (int nn = 0; nn < 2; ++nn) {
            const int hh = gw * 32 + nn * 16 + fr;
            const float2 m0 = *(const float2*)(smem + HOF + hh * 8);
            const float2 m1 = *(const float2*)(smem + HOF + 512 + hh * 8);
            const float cin = (sw == 0) ? cc[nn]
                                        : __builtin_fmaf(m0.x, cc[nn], m0.y);
            #pragma unroll
            for (int m = 0; m < 4; ++m) {
                float cr = __builtin_fmaf(FsS[nn][m], cin, GsS[nn][m]);
                #pragma unroll
                for (int j = 0; j < 4; ++j) {
                    cr = __builtin_fmaf(acc[m][2 + nn][j], cr, acc[m][nn][j]);
                    const int sg = b * S_ + sc * SC + sw * 64 + m * 16 + fq * 4 + j;
                    out[(size_t)sg * H_ + hs * HS + hh] = acc[m][4 + nn][j] * cr;
                }
            }
            cc[nn] = __builtin_fmaf(m1.x, __builtin_fmaf(m0.x, cc[nn], m0.y), m1.y);
        }
        asm volatile("s_waitcnt lgkmcnt(0)" ::: "memory");
        __builtin_amdgcn_s_barrier();   // handoff consumed before kt0 restage
    }

    // c_last tail: [1,B,H] appended after [B,S,H]
    if (sw == 0 && fq == 0) {
        #pragma unroll
        for (int nn = 0; nn < 2; ++nn)
            out[(size_t)B_ * S_ * H_ + b * H_ + hs * HS + gw * 32 + nn * 16 + fr] = cc[nn];
    }
}

extern "C" void kernel_launch(void* const* d_in, const int* in_sizes, int n_in,
                              void* d_out, int out_size, void* d_ws, size_t ws_size,
                              hipStream_t stream) {
    const float* x = (const float*)d_in[0];
    const float* h = (const float*)d_in[1];
    const float* W = (const float*)d_in[2];
    const float* b = (const float*)d_in[3];
    float* out = (float*)d_out;

    _Float16* xh = (_Float16*)d_ws;
    _Float16* Wh = xh + (size_t)B_ * S_ * K_;

    hipFuncSetAttribute((const void*)qrnn_fused,
                        hipFuncAttributeMaxDynamicSharedMemorySize, LDS_BYTES);

    const int n8x = B_ * S_ * K_ / 8;   // 1048576
    const int n8w = 3 * H_ * K_ / 8;    // 196608
    cvt_xw<<<(n8x + n8w + 255) / 256, 256, 0, stream>>>(x, xh, n8x, W, Wh, n8w);

    qrnn_fused<<<B_ * (H_ / HS), 256, LDS_BYTES, stream>>>(xh, Wh, b, h, out);
}